// Round 1
// baseline (7731.948 us; speedup 1.0000x reference)
//
#include <hip/hip_runtime.h>
#include <hip/hip_bf16.h>

#define IGNORE_INDEX (-100)

static constexpr int N_TOK = 8192;
static constexpr int DIM   = 4096;
static constexpr int VOCAB = 32000;

static constexpr int BM = 128;   // rows per block
static constexpr int BN = 128;   // vocab cols per V-tile
static constexpr int BK = 32;    // K step
static constexpr int VT = 10;    // V-tiles per chunk (block loops these, online LSE)
static constexpr int CHUNKS = VOCAB / (BN * VT); // 25
static constexpr int SLD = 40;   // LDS row stride in bf16 elems (80B: 16B-aligned, bank-spread)

typedef __attribute__((ext_vector_type(8))) __bf16 bf16x8;
typedef __attribute__((ext_vector_type(4))) float  f32x4;

// ---------------- kernel 1: exact fp32 target logit per row ----------------
__global__ __launch_bounds__(64) void ce_tgt_kernel(const float* __restrict__ A,
                                                    const float* __restrict__ W,
                                                    const int* __restrict__ target,
                                                    float* __restrict__ tgt_logit)
{
    const int r    = blockIdx.x;
    const int lane = threadIdx.x;
    const int t    = target[r];
    if (t == IGNORE_INDEX) { if (lane == 0) tgt_logit[r] = 0.f; return; }
    const float* a = A + (size_t)r * DIM;
    const float* w = W + (size_t)t * DIM;
    float s = 0.f;
    #pragma unroll
    for (int k = lane * 4; k < DIM; k += 64 * 4) {
        const float4 av = *(const float4*)(a + k);
        const float4 wv = *(const float4*)(w + k);
        s += av.x * wv.x + av.y * wv.y + av.z * wv.z + av.w * wv.w;
    }
    #pragma unroll
    for (int off = 32; off > 0; off >>= 1) s += __shfl_xor(s, off);
    if (lane == 0) tgt_logit[r] = s;
}

// ---------------- kernel 2: fused GEMM + online per-row (max, sumexp) ------
// grid: (N_TOK/BM, CHUNKS); block 256 = 4 waves arranged 2x2, each wave owns 64x64
__global__ __launch_bounds__(256) void ce_main_kernel(const float* __restrict__ A,
                                                      const float* __restrict__ W,
                                                      float* __restrict__ pmax,
                                                      float* __restrict__ psum)
{
    __shared__ __attribute__((aligned(16))) __bf16 As[BM * SLD];
    __shared__ __attribute__((aligned(16))) __bf16 Bs[BN * SLD];
    __shared__ float wmaxs[2][BM];
    __shared__ float wsums[2][BM];

    const int tid  = threadIdx.x;
    const int lane = tid & 63;
    const int wid  = tid >> 6;   // 0..3
    const int wr   = wid >> 1;   // wave row (0..1) -> rows wr*64..wr*64+63
    const int wc   = wid & 1;    // wave col (0..1) -> cols wc*64..wc*64+63
    const int l15  = lane & 15;
    const int lg   = lane >> 4;  // 0..3
    const int n0   = blockIdx.x * BM;
    const int chunk = blockIdx.y;

    // staging: thread t loads 16 contiguous floats of one row (A and W)
    const int srow = tid >> 1;           // 0..127
    const int scol = (tid & 1) * 16;     // 0 or 16
    const int kLds = srow * SLD + scol;  // bf16 elem offset (16B-aligned)

    const float* abase = A + (size_t)(n0 + srow) * DIM + scol;

    // per-row online state lives in the thread that owns row (tid < 128)
    float mrun = -INFINITY;
    float srun = 0.f;

    for (int vt = 0; vt < VT; ++vt) {
        const int v0 = chunk * (BN * VT) + vt * BN;
        const float* wbase = W + (size_t)(v0 + srow) * DIM + scol;

        f32x4 acc[4][4];
        #pragma unroll
        for (int m = 0; m < 4; ++m)
            #pragma unroll
            for (int n = 0; n < 4; ++n) acc[m][n] = (f32x4)0.f;

        for (int kb = 0; kb < DIM / BK; ++kb) {
            __syncthreads();
            {   // stage A tile (fp32 -> bf16)
                const float* ap = abase + kb * BK;
                const float4 a0 = *(const float4*)(ap + 0);
                const float4 a1 = *(const float4*)(ap + 4);
                const float4 a2 = *(const float4*)(ap + 8);
                const float4 a3 = *(const float4*)(ap + 12);
                bf16x8 p0, p1;
                p0[0]=(__bf16)a0.x; p0[1]=(__bf16)a0.y; p0[2]=(__bf16)a0.z; p0[3]=(__bf16)a0.w;
                p0[4]=(__bf16)a1.x; p0[5]=(__bf16)a1.y; p0[6]=(__bf16)a1.z; p0[7]=(__bf16)a1.w;
                p1[0]=(__bf16)a2.x; p1[1]=(__bf16)a2.y; p1[2]=(__bf16)a2.z; p1[3]=(__bf16)a2.w;
                p1[4]=(__bf16)a3.x; p1[5]=(__bf16)a3.y; p1[6]=(__bf16)a3.z; p1[7]=(__bf16)a3.w;
                *reinterpret_cast<bf16x8*>(&As[kLds])     = p0;
                *reinterpret_cast<bf16x8*>(&As[kLds + 8]) = p1;
                // stage W tile (rows are vocab entries)
                const float* wp = wbase + kb * BK;
                const float4 b0 = *(const float4*)(wp + 0);
                const float4 b1 = *(const float4*)(wp + 4);
                const float4 b2 = *(const float4*)(wp + 8);
                const float4 b3 = *(const float4*)(wp + 12);
                bf16x8 q0, q1;
                q0[0]=(__bf16)b0.x; q0[1]=(__bf16)b0.y; q0[2]=(__bf16)b0.z; q0[3]=(__bf16)b0.w;
                q0[4]=(__bf16)b1.x; q0[5]=(__bf16)b1.y; q0[6]=(__bf16)b1.z; q0[7]=(__bf16)b1.w;
                q1[0]=(__bf16)b2.x; q1[1]=(__bf16)b2.y; q1[2]=(__bf16)b2.z; q1[3]=(__bf16)b2.w;
                q1[4]=(__bf16)b3.x; q1[5]=(__bf16)b3.y; q1[6]=(__bf16)b3.z; q1[7]=(__bf16)b3.w;
                *reinterpret_cast<bf16x8*>(&Bs[kLds])     = q0;
                *reinterpret_cast<bf16x8*>(&Bs[kLds + 8]) = q1;
            }
            __syncthreads();

            bf16x8 af[4], bfr[4];
            #pragma unroll
            for (int m = 0; m < 4; ++m)
                af[m] = *reinterpret_cast<const bf16x8*>(&As[(wr*64 + m*16 + l15) * SLD + lg*8]);
            #pragma unroll
            for (int n = 0; n < 4; ++n)
                bfr[n] = *reinterpret_cast<const bf16x8*>(&Bs[(wc*64 + n*16 + l15) * SLD + lg*8]);
            #pragma unroll
            for (int m = 0; m < 4; ++m)
                #pragma unroll
                for (int n = 0; n < 4; ++n)
                    acc[m][n] = __builtin_amdgcn_mfma_f32_16x16x32_bf16(af[m], bfr[n], acc[m][n], 0, 0, 0);
        }

        // ---- epilogue for this 128-col tile: per-row max & sumexp ----
        // C layout (m89-verified): col = n*16 + (lane&15), row = m*16 + (lane>>4)*4 + j
        #pragma unroll
        for (int m = 0; m < 4; ++m) {
            #pragma unroll
            for (int j = 0; j < 4; ++j) {
                float vmax = fmaxf(fmaxf(acc[m][0][j], acc[m][1][j]),
                                   fmaxf(acc[m][2][j], acc[m][3][j]));
                #pragma unroll
                for (int off = 1; off < 16; off <<= 1) vmax = fmaxf(vmax, __shfl_xor(vmax, off));
                float vsum = 0.f;
                #pragma unroll
                for (int n = 0; n < 4; ++n) vsum += expf(acc[m][n][j] - vmax);
                #pragma unroll
                for (int off = 1; off < 16; off <<= 1) vsum += __shfl_xor(vsum, off);
                if (l15 == 0) {
                    const int rloc = wr*64 + m*16 + lg*4 + j;
                    wmaxs[wc][rloc] = vmax;
                    wsums[wc][rloc] = vsum;
                }
            }
        }
        __syncthreads();
        if (tid < BM) {  // thread tid owns row tid: merge the two wave-halves, then online-merge
            const float m0 = wmaxs[0][tid], m1 = wmaxs[1][tid];
            const float mw = fmaxf(m0, m1);
            const float sw = wsums[0][tid] * expf(m0 - mw) + wsums[1][tid] * expf(m1 - mw);
            const float mn = fmaxf(mrun, mw);
            srun = srun * expf(mrun - mn) + sw * expf(mw - mn);
            mrun = mn;
        }
        // next vt's first __syncthreads orders wmaxs reuse
    }

    if (tid < BM) {
        pmax[(size_t)(n0 + tid) * CHUNKS + chunk] = mrun;
        psum[(size_t)(n0 + tid) * CHUNKS + chunk] = srun;
    }
}

// ---------------- kernel 3: per-row combine + per-block partial loss -------
__global__ __launch_bounds__(256) void ce_reduce_kernel(const float* __restrict__ pmax,
                                                        const float* __restrict__ psum,
                                                        const float* __restrict__ tgt_logit,
                                                        const int* __restrict__ target,
                                                        float* __restrict__ bsum,
                                                        float* __restrict__ bcnt)
{
    const int r = blockIdx.x * 256 + threadIdx.x;
    float loss = 0.f, cnt = 0.f;
    {
        const float* pm = pmax + (size_t)r * CHUNKS;
        const float* ps = psum + (size_t)r * CHUNKS;
        float M = -INFINITY;
        #pragma unroll
        for (int c = 0; c < CHUNKS; ++c) M = fmaxf(M, pm[c]);
        float S = 0.f;
        #pragma unroll
        for (int c = 0; c < CHUNKS; ++c) S += ps[c] * expf(pm[c] - M);
        const int t = target[r];
        if (t != IGNORE_INDEX) { loss = (M + logf(S)) - tgt_logit[r]; cnt = 1.f; }
    }
    #pragma unroll
    for (int off = 32; off > 0; off >>= 1) { loss += __shfl_xor(loss, off); cnt += __shfl_xor(cnt, off); }
    __shared__ float sl[4], sc[4];
    const int w = threadIdx.x >> 6;
    if ((threadIdx.x & 63) == 0) { sl[w] = loss; sc[w] = cnt; }
    __syncthreads();
    if (threadIdx.x == 0) {
        bsum[blockIdx.x] = sl[0] + sl[1] + sl[2] + sl[3];
        bcnt[blockIdx.x] = sc[0] + sc[1] + sc[2] + sc[3];
    }
}

// ---------------- kernel 4: final mean ----------------
__global__ __launch_bounds__(64) void ce_final_kernel(const float* __restrict__ bsum,
                                                      const float* __restrict__ bcnt,
                                                      float* __restrict__ out)
{
    const int lane = threadIdx.x;
    float s = (lane < N_TOK / 256) ? bsum[lane] : 0.f;
    float c = (lane < N_TOK / 256) ? bcnt[lane] : 0.f;
    #pragma unroll
    for (int off = 32; off > 0; off >>= 1) { s += __shfl_xor(s, off); c += __shfl_xor(c, off); }
    if (lane == 0) out[0] = s / fmaxf(c, 1.f);
}

extern "C" void kernel_launch(void* const* d_in, const int* in_sizes, int n_in,
                              void* d_out, int out_size, void* d_ws, size_t ws_size,
                              hipStream_t stream) {
    (void)in_sizes; (void)n_in; (void)out_size; (void)ws_size;
    const float* A      = (const float*)d_in[0];
    const float* W      = (const float*)d_in[1];
    const int*   target = (const int*)d_in[2];
    float*       out    = (float*)d_out;

    float* ws        = (float*)d_ws;
    float* tgt_logit = ws;                          // 8192
    float* pmax      = tgt_logit + N_TOK;           // 8192*25
    float* psum      = pmax + (size_t)N_TOK * CHUNKS;
    float* bsum      = psum + (size_t)N_TOK * CHUNKS; // 32
    float* bcnt      = bsum + (N_TOK / 256);          // 32

    ce_tgt_kernel<<<N_TOK, 64, 0, stream>>>(A, W, target, tgt_logit);
    ce_main_kernel<<<dim3(N_TOK / BM, CHUNKS), 256, 0, stream>>>(A, W, pmax, psum);
    ce_reduce_kernel<<<N_TOK / 256, 256, 0, stream>>>(pmax, psum, tgt_logit, target, bsum, bcnt);
    ce_final_kernel<<<1, 64, 0, stream>>>(bsum, bcnt, out);
}